// Round 8
// baseline (107.774 us; speedup 1.0000x reference)
//
#include <hip/hip_runtime.h>

#define BATCH   8
#define HH      512
#define WW      512
#define IMGPIX  (HH * WW)          // 262144 = 1<<18
#define NPIX    (BATCH * IMGPIX)   // 2097152
#define NWORDS  (NPIX / 64)        // 32768 packed words
#define WPR     8                  // 64-bit words per 512-px row
#define FPSCALE 262144.0           // 2^18 fixed-point scale for i64 reduction

// ---- skeleton partitioning ----
#define BPI     32                 // blocks per image (256 total, 1/CU)
#define GZ      16                 // ghost rows each side == substeps per chunk
#define OWN     16                 // owned rows per block (HH / BPI)
#define ROWS    (OWN + 2 * GZ)     // 48 data rows in LDS
#define LROWS   (ROWS + 2)         // +2 guard rows (always zero)
#define LROW    10                 // 8 data words + 2 guard cols (always zero)
#define STHREADS (ROWS * WPR)      // 384 threads (6 waves)
#define MAXC    32                 // chunk cap (512 substeps = 256 pairs, worst case)
#define NBLK    (BATCH * BPI)      // 256 blocks

typedef unsigned long long u64;
typedef unsigned int u32;

// ---------------- kernel 1: CE loss + packed mask + zero accumulators/barrier slots ----------------
__global__ void prep_kernel(const float* __restrict__ pred, const int* __restrict__ target,
                            float* __restrict__ L, u64* __restrict__ xp,
                            u64* __restrict__ acc64, u32* __restrict__ ticket,
                            u32* __restrict__ bar2) {
    int j = blockIdx.x * blockDim.x + threadIdx.x;   // 0 .. NPIX/4
    if (j == 0) { acc64[0] = 0ULL; ticket[0] = 0u; }
    if (j < BATCH * MAXC) bar2[j] = 0u;              // per-image per-chunk barrier slots
    int lane = j & 63;
    int pixbase = (j >> 6) << 8;                     // this wave's 256-px tile
    #pragma unroll
    for (int k = 0; k < 4; ++k) {
        int i = pixbase + (k << 6) + lane;
        int b = i >> 18;
        int hw = i & (IMGPIX - 1);
        float p0 = pred[((size_t)(2 * b) << 18) + hw];
        float p1 = pred[((size_t)(2 * b + 1) << 18) + hw];
        float m = fmaxf(p0, p1);
        float lse = m + logf(expf(p0 - m) + expf(p1 - m));
        int t = target[i];
        L[i] = lse - (t ? p1 : p0);                  // -log_softmax[target]
        u64 word = __ballot(p1 > p0);
        if (lane == 0) xp[(pixbase >> 6) + k] = word;
    }
}

// ---------------- bit-sliced helpers ----------------
#define FA(a,b,c,s,cy) { u64 _x = (a)^(b); (s) = _x^(c); (cy) = ((a)&(b)) | ((c)&_x); }
#define HA(a,b,s,cy)   { (s) = (a)^(b); (cy) = (a)&(b); }

__device__ __forceinline__ u64 zs_word(int first,
    u64 Up, u64 Uc, u64 Un, u64 Mp, u64 Mc, u64 Mn, u64 Dp, u64 Dc, u64 Dn,
    u64* delp)
{
    if (Mc == 0ULL) { *delp = 0ULL; return 0ULL; }
    u64 P2 = Uc, P6 = Dc;
    u64 P3 = (Uc >> 1) | (Un << 63);
    u64 P4 = (Mc >> 1) | (Mn << 63);
    u64 P5 = (Dc >> 1) | (Dn << 63);
    u64 P9 = (Uc << 1) | (Up >> 63);
    u64 P8 = (Mc << 1) | (Mp >> 63);
    u64 P7 = (Dc << 1) | (Dp >> 63);

    u64 sa,ca, sb,cb, sc,cc, b0,cd, sd,ce, b1,cf, b2,b3;
    FA(P2,P3,P4, sa,ca);
    FA(P5,P6,P7, sb,cb);
    FA(P8,P9,sa, sc,cc);
    HA(sb,sc,    b0,cd);
    FA(ca,cb,cc, sd,ce);
    HA(sd,cd,    b1,cf);
    HA(ce,cf,    b2,b3);
    u64 ge2 = b1 | b2 | b3;
    u64 le6 = ~(b3 | (b0 & b1 & b2));

    u64 e, seen, two = 0;
    seen = (~P2) & P3;
    e = (~P3) & P4; two |= seen & e; seen |= e;
    e = (~P4) & P5; two |= seen & e; seen |= e;
    e = (~P5) & P6; two |= seen & e; seen |= e;
    e = (~P6) & P7; two |= seen & e; seen |= e;
    e = (~P7) & P8; two |= seen & e; seen |= e;
    e = (~P8) & P9; two |= seen & e; seen |= e;
    e = (~P9) & P2; two |= seen & e; seen |= e;
    u64 A1 = seen & ~two;

    u64 c34;
    if (first) { u64 t = P4 & P6; c34 = t & (P2 | P8); }
    else       { u64 t = P2 & P8; c34 = t & (P4 | P6); }

    u64 del = Mc & ge2 & le6 & A1 & ~c34;
    *delp = del;
    return Mc ^ del;
}

// ---------------- packed 9x9 count helpers ----------------
struct Planes { u64 p0, p1, p2, p3; };

__device__ __forceinline__ Planes vcount9(const u64 r[9]) {
    u64 s0,c0, s1,c1, s2,c2, p0,t0, t1,t2, p1,t3, p2,p3;
    FA(r[0],r[1],r[2], s0,c0);
    FA(r[3],r[4],r[5], s1,c1);
    FA(r[6],r[7],r[8], s2,c2);
    FA(s0,s1,s2, p0,t0);
    FA(c0,c1,c2, t1,t2);
    HA(t0,t1,    p1,t3);
    HA(t2,t3,    p2,p3);
    Planes P; P.p0 = p0; P.p1 = p1; P.p2 = p2; P.p3 = p3; return P;
}

__device__ __forceinline__ u64 spread8(u64 bb) {
    u64 s = (bb * 0x0101010101010101ULL) & 0x8040201008040201ULL;
    return ((s + 0x7f7f7f7f7f7f7f7fULL) >> 7) & 0x0101010101010101ULL;
}

__device__ __forceinline__ u64 vbytes(const Planes& P, int g) {
    int s = 8 * g;
    return  spread8((P.p0 >> s) & 0xFFULL)
         + (spread8((P.p1 >> s) & 0xFFULL) << 1)
         + (spread8((P.p2 >> s) & 0xFFULL) << 2)
         + (spread8((P.p3 >> s) & 0xFFULL) << 3);
}

// ---------------- kernel 2: skeletonize (guard-padded LDS, adaptive chunks) + fused tail ----------------
__global__ __launch_bounds__(STHREADS)
void skel_kernel(const u64* __restrict__ xp, u64* __restrict__ xs,
                 const float* __restrict__ L,
                 u64* __restrict__ acc64, u32* __restrict__ ticket,
                 u32* __restrict__ bar2, float* __restrict__ out)
{
    __shared__ u64 lds[2][LROWS * LROW];   // 2 x 50 x 10 x 8B = 8000 B, guard ring always 0
    __shared__ u32 chflag[GZ];
    __shared__ u32 bch;                    // any owned-row deletion this chunk
    __shared__ u32 sh_ch;
    __shared__ float sw[STHREADS / 64];

    const int blk  = blockIdx.x;
    const int img  = blk >> 5;             // blk / BPI
    const int part = blk & (BPI - 1);
    const int t    = threadIdx.x;
    const int rL   = t >> 3;               // data row 0..47
    const int wc   = t & 7;                // word column 0..7
    const int gr0  = part * OWN - GZ;      // global row of data row 0
    const int base = (rL + 1) * LROW + (wc + 1);
    const bool owned = (rL >= GZ) && (rL < GZ + OWN);
    const bool ghost = !owned;
    const int gr = gr0 + rL;
    const bool inimg = (unsigned)gr < (unsigned)HH;
    const u64* src = xp + ((size_t)img << 12);

    // ---- init: zero both buffers (incl guard ring), then fill data rows
    for (int k = t; k < 2 * LROWS * LROW; k += STHREADS) ((u64*)lds)[k] = 0ULL;
    if (t < GZ) chflag[t] = 0u;
    if (t == GZ * 8) bch = 0u;   // any thread id works; use a fixed one
    __syncthreads();
    if (inimg) lds[0][base] = src[gr * WPR + wc];
    __syncthreads();

    // ---- chunk loop
    for (int chunk = 0; chunk < MAXC; ++chunk) {
        int cur = 0;
        for (int s = 0; s < GZ; ++s) {
            const u64* __restrict__ B = lds[cur];
            u64* __restrict__ W = lds[cur ^ 1];
            u64 Uc = B[base - LROW], Up = B[base - LROW - 1], Un = B[base - LROW + 1];
            u64 Mc = B[base],        Mp = B[base - 1],        Mn = B[base + 1];
            u64 Dc = B[base + LROW], Dp = B[base + LROW - 1], Dn = B[base + LROW + 1];
            u64 del;
            u64 nw = zs_word((s & 1) == 0, Up, Uc, Un, Mp, Mc, Mn, Dp, Dc, Dn, &del);
            W[base] = nw;
            if (del) { chflag[s] = 1u; if (owned) bch = 1u; }   // benign races
            __syncthreads();
            cur ^= 1;
            // local fixpoint for BOTH parities -> remaining substeps are identity.
            // Break only at odd s so the executed count is even (state ends in lds[0]).
            if ((s & 1) && chflag[s] == 0u && chflag[s - 1] == 0u) break;
        }
        // state is in lds[0] (even number of flips)

        // ---- publish owned rows to the parity halo buffer
        u64* xsp = xs + (size_t)(chunk & 1) * NWORDS + ((size_t)img << 12);
        if (owned) xsp[gr * WPR + wc] = lds[0][base];
        __threadfence();
        __syncthreads();                     // all publishes drained (barrier waits vmcnt)

        // ---- one packed atomic per block: low16 = arrivals, high16 = changed count
        if (t == 0) {
            u32 add = 1u | (bch << 16);
            u32* slot = &bar2[img * MAXC + chunk];
            atomicAdd(slot, add);
            u32 v;
            while (((v = __hip_atomic_load(slot, __ATOMIC_ACQUIRE, __HIP_MEMORY_SCOPE_AGENT))
                    & 0xFFFFu) < (u32)BPI)
                __builtin_amdgcn_s_sleep(2);
            sh_ch = v >> 16;                 // total changed blocks this chunk (image-wide)
        }
        __syncthreads();
        u32 anych = sh_ch;
        if (!anych) break;                   // global fixpoint: lds[0] is exact everywhere

        // ---- reload ghosts from neighbors' published rows; reset chunk flags
        if (ghost && inimg) lds[0][base] = xsp[gr * WPR + wc];
        if (t < GZ) chflag[t] = 0u;
        if (t == GZ * 8) bch = 0u;
        __syncthreads();
    }

    // ================= fused tail: E -> 9x9 count -> weighted sum =================
    // lds[0] holds the exact final skeleton on all 48 data rows (ghosts ±16 >> ±5 needed).
    u64* Eb = lds[1];                        // guards of lds[1] still zero
    if (rL >= GZ - 4 && rL < GZ + OWN + 4) { // E rows 12..35 cover all 9-row windows of owned
        const u64* B = lds[0];
        u64 Uc = B[base - LROW], Up = B[base - LROW - 1], Un = B[base - LROW + 1];
        u64 Mc = B[base],        Mp = B[base - 1],        Mn = B[base + 1];
        u64 Dc = B[base + LROW], Dp = B[base + LROW - 1], Dn = B[base + LROW + 1];
        u64 P2 = Uc, P6 = Dc;
        u64 P3 = (Uc >> 1) | (Un << 63);
        u64 P4 = (Mc >> 1) | (Mn << 63);
        u64 P5 = (Dc >> 1) | (Dn << 63);
        u64 P9 = (Uc << 1) | (Up >> 63);
        u64 P8 = (Mc << 1) | (Mp >> 63);
        u64 P7 = (Dc << 1) | (Dp >> 63);
        u64 e, seen, two = 0;
        seen = P2;
        e = P3; two |= seen & e; seen |= e;
        e = P4; two |= seen & e; seen |= e;
        e = P5; two |= seen & e; seen |= e;
        e = P6; two |= seen & e; seen |= e;
        e = P7; two |= seen & e; seen |= e;
        e = P8; two |= seen & e; seen |= e;
        e = P9; two |= seen & e; seen |= e;
        Eb[base] = Mc & seen & ~two;         // endpoint: exactly one 8-neighbor
    }
    __syncthreads();

    float acc = 0.0f;
    if (owned) {
        u64 rows0[9], rows1[9], rows2[9];
        #pragma unroll
        for (int dh = -4; dh <= 4; ++dh) {
            int rb = base + dh * LROW;
            rows0[dh + 4] = Eb[rb - 1];
            rows1[dh + 4] = Eb[rb];
            rows2[dh + 4] = Eb[rb + 1];
        }
        Planes Pm = vcount9(rows0);
        Planes Pc = vcount9(rows1);
        Planes Pp = vcount9(rows2);

        u64 v[10];
        v[0] = vbytes(Pm, 7);
        #pragma unroll
        for (int g = 0; g < 8; ++g) v[g + 1] = vbytes(Pc, g);
        v[9] = vbytes(Pp, 0);

        const float4* Lr = (const float4*)(L + ((size_t)img << 18) + (size_t)gr * WW + (wc << 6));
        #pragma unroll
        for (int g = 0; g < 8; ++g) {
            u64 a = v[g + 1], lo = v[g], hi = v[g + 2];
            u64 n = a;
            #pragma unroll
            for (int d = 1; d <= 4; ++d) {
                n += (a >> (8 * d)) | (hi << (64 - 8 * d));
                n += (a << (8 * d)) | (lo >> (64 - 8 * d));
            }
            float4 f0 = Lr[2 * g], f1 = Lr[2 * g + 1];
            #pragma unroll
            for (int jj = 0; jj < 8; ++jj) {
                int cnt = (int)((n >> (8 * jj)) & 0xFFULL);
                float wgt = cnt ? (float)(60 * cnt) : 1.0f;   // Wmap = 60*n + [n==0]
                float lv = (jj < 4) ? ((jj == 0) ? f0.x : (jj == 1) ? f0.y : (jj == 2) ? f0.z : f0.w)
                                    : ((jj == 4) ? f1.x : (jj == 5) ? f1.y : (jj == 6) ? f1.z : f1.w);
                acc += wgt * lv;
            }
        }
    }

    // wave shuffle reduce, then cross-wave via LDS
    #pragma unroll
    for (int off = 32; off > 0; off >>= 1) acc += __shfl_down(acc, off, 64);
    if ((t & 63) == 0) sw[t >> 6] = acc;
    __syncthreads();
    if (t == 0) {
        float s = 0.0f;
        #pragma unroll
        for (int w = 0; w < STHREADS / 64; ++w) s += sw[w];
        u64 vfx = (u64)(long long)llrintf(s * (float)FPSCALE);
        atomicAdd(acc64, vfx);
        __threadfence();
        u32 tk = atomicAdd(ticket, 1u);
        if (tk == (u32)(NBLK - 1)) {
            __threadfence();
            u64 total = __hip_atomic_load(acc64, __ATOMIC_RELAXED, __HIP_MEMORY_SCOPE_AGENT);
            out[0] = (float)((double)(long long)total / (FPSCALE * (double)NPIX));
        }
    }
}

extern "C" void kernel_launch(void* const* d_in, const int* in_sizes, int n_in,
                              void* d_out, int out_size, void* d_ws, size_t ws_size,
                              hipStream_t stream) {
    const float* pred = (const float*)d_in[0];
    const int* target = (const int*)d_in[1];
    float* out = (float*)d_out;
    char* ws = (char*)d_ws;

    // ws layout (bytes):
    //   [0,        8388608)  L       float[NPIX]
    //   [8388608,  8650752)  xp      u64[NWORDS]    packed mask
    //   [8650752,  9175040)  xs      u64[2*NWORDS]  parity-buffered halo exchange
    //   [9175040,  9175048)  acc64   u64
    //   [9175048,  9175052)  ticket  u32
    //   [9175052,  9176076)  bar2    u32[8*32]      per-image per-chunk packed barrier
    float* L    = (float*)(ws);
    u64* xp     = (u64*)(ws + 8388608);
    u64* xs     = (u64*)(ws + 8650752);
    u64* acc64  = (u64*)(ws + 9175040);
    u32* ticket = (u32*)(ws + 9175048);
    u32* bar2   = (u32*)(ws + 9175052);

    prep_kernel<<<dim3(NPIX / 4 / 256), dim3(256), 0, stream>>>(pred, target, L, xp,
                                                                acc64, ticket, bar2);

    {
        void* args[] = { (void*)&xp, (void*)&xs, (void*)&L, (void*)&acc64,
                         (void*)&ticket, (void*)&bar2, (void*)&out };
        hipLaunchCooperativeKernel((void*)skel_kernel, dim3(NBLK), dim3(STHREADS),
                                   args, 0, stream);
    }
}

// Round 9
// 61.770 us; speedup vs baseline: 1.7448x; 1.7448x over previous
//
#include <hip/hip_runtime.h>

#define BATCH   8
#define HH      512
#define WW      512
#define IMGPIX  (HH * WW)          // 262144 = 1<<18
#define NPIX    (BATCH * IMGPIX)   // 2097152
#define NWORDS  (NPIX / 64)        // 32768 packed words
#define WPR     8                  // 64-bit words per 512-px row
#define LDSTR   9                  // padded LDS row stride in words
#define FPSCALE 262144.0           // 2^18 fixed-point scale for i64 reduction
#define MAXPAIR 256

typedef unsigned long long u64;
typedef unsigned int u32;

// ---------------- kernel 1: CE loss + packed binary mask + zero accumulators ----------------
__global__ void prep_kernel(const float* __restrict__ pred, const int* __restrict__ target,
                            float* __restrict__ L, u64* __restrict__ xp,
                            u64* __restrict__ acc64, u32* __restrict__ ticket) {
    int i = blockIdx.x * blockDim.x + threadIdx.x;
    if (i == 0) { acc64[0] = 0ULL; ticket[0] = 0u; }
    if (i >= NPIX) return;
    int b = i >> 18;
    int hw = i & (IMGPIX - 1);
    float p0 = pred[((size_t)(2 * b) << 18) + hw];
    float p1 = pred[((size_t)(2 * b + 1) << 18) + hw];
    float m = fmaxf(p0, p1);
    float lse = m + logf(expf(p0 - m) + expf(p1 - m));
    int t = target[i];
    L[i] = lse - (t ? p1 : p0);            // -log_softmax[target]
    u64 word = __ballot(p1 > p0);          // 64 consecutive pixels per wave
    if ((threadIdx.x & 63) == 0) xp[i >> 6] = word;
}

// ---------------- bit-sliced helpers ----------------
#define FA(a,b,c,s,cy) { u64 _x = (a)^(b); (s) = _x^(c); (cy) = ((a)&(b)) | ((c)&_x); }
#define HA(a,b,s,cy)   { (s) = (a)^(b); (cy) = (a)&(b); }

// One ZS substep over a row of 8 words held in M[]; U/D are neighbor rows.
// Updates M in place; returns OR of deleted bits.
template<int FIRST>
__device__ __forceinline__ u64 zs_row(const u64* __restrict__ U, u64* __restrict__ M,
                                      const u64* __restrict__ D)
{
    u64 ch = 0;
    #pragma unroll
    for (int k = 0; k < WPR; ++k) {
        u64 Mc = M[k];
        if (Mc == 0ULL) continue;
        u64 Uc = U[k], Dc = D[k];
        u64 Up = k     ? U[k-1] : 0ULL;
        u64 Mp = k     ? M[k-1] : 0ULL;
        u64 Dp = k     ? D[k-1] : 0ULL;
        u64 Un = k < 7 ? U[k+1] : 0ULL;
        u64 Mn = k < 7 ? M[k+1] : 0ULL;
        u64 Dn = k < 7 ? D[k+1] : 0ULL;
        u64 P2 = Uc, P6 = Dc;
        u64 P3 = (Uc >> 1) | (Un << 63);
        u64 P4 = (Mc >> 1) | (Mn << 63);
        u64 P5 = (Dc >> 1) | (Dn << 63);
        u64 P9 = (Uc << 1) | (Up >> 63);
        u64 P8 = (Mc << 1) | (Mp >> 63);
        u64 P7 = (Dc << 1) | (Dp >> 63);

        u64 sa,ca, sb,cb, sc,cc, b0,cd, sd,ce, b1,cf, b2,b3;
        FA(P2,P3,P4, sa,ca);
        FA(P5,P6,P7, sb,cb);
        FA(P8,P9,sa, sc,cc);
        HA(sb,sc,    b0,cd);
        FA(ca,cb,cc, sd,ce);
        HA(sd,cd,    b1,cf);
        HA(ce,cf,    b2,b3);
        u64 ge2 = b1 | b2 | b3;
        u64 le6 = ~(b3 | (b0 & b1 & b2));

        u64 e, seen, two = 0;
        seen = (~P2) & P3;
        e = (~P3) & P4; two |= seen & e; seen |= e;
        e = (~P4) & P5; two |= seen & e; seen |= e;
        e = (~P5) & P6; two |= seen & e; seen |= e;
        e = (~P6) & P7; two |= seen & e; seen |= e;
        e = (~P7) & P8; two |= seen & e; seen |= e;
        e = (~P8) & P9; two |= seen & e; seen |= e;
        e = (~P9) & P2; two |= seen & e; seen |= e;
        u64 A1 = seen & ~two;

        u64 c34;
        if (FIRST) { u64 t = P4 & P6; c34 = t & (P2 | P8); }
        else       { u64 t = P2 & P8; c34 = t & (P4 | P6); }

        u64 del = Mc & ge2 & le6 & A1 & ~c34;
        M[k] = Mc ^ del;
        ch |= del;
    }
    return ch;
}

// ---------------- kernel 2: single-block-per-image skeletonize + packed endpoints ----------------
// 8 blocks x 512 threads (thread = row). Own row lives in REGISTERS; LDS is the shared image.
__global__ __launch_bounds__(512)
void skel_kernel(const u64* __restrict__ xp, u64* __restrict__ eg)
{
    __shared__ u64 img[(HH + 2) * LDSTR];  // guard rows 0 and HH+1 stay zero: 37,008 B
    const int b = blockIdx.x;
    const int h = threadIdx.x;
    const int base = (h + 1) * LDSTR;      // own row origin in LDS

    // zero guard rows once
    if (h < 2 * LDSTR) {
        int idx = (h < LDSTR) ? h : ((HH + 1) * LDSTR + (h - LDSTR));
        img[idx] = 0ULL;
    }

    u64 M[WPR], U[WPR], D[WPR];
    const u64* src = xp + ((size_t)b << 12) + (size_t)h * WPR;
    #pragma unroll
    for (int k = 0; k < WPR; ++k) { M[k] = src[k]; img[base + k] = M[k]; }
    __syncthreads();

    for (int p = 0; p < MAXPAIR; ++p) {
        // ---- substep A (first = true)
        #pragma unroll
        for (int k = 0; k < WPR; ++k) { U[k] = img[base - LDSTR + k]; D[k] = img[base + LDSTR + k]; }
        __syncthreads();                                   // reads done before writes
        u64 chA = zs_row<1>(U, M, D);
        if (chA) {
            #pragma unroll
            for (int k = 0; k < WPR; ++k) img[base + k] = M[k];
        }
        __syncthreads();                                   // writes visible

        // ---- substep B (first = false)
        #pragma unroll
        for (int k = 0; k < WPR; ++k) { U[k] = img[base - LDSTR + k]; D[k] = img[base + LDSTR + k]; }
        __syncthreads();
        u64 chB = zs_row<0>(U, M, D);
        if (chB) {
            #pragma unroll
            for (int k = 0; k < WPR; ++k) img[base + k] = M[k];
        }
        if (!__syncthreads_or((chA | chB) != 0ULL)) break; // pair deleted nothing anywhere
    }

    // ---- endpoints E = skel & (exactly one 8-neighbor); state: img + M regs (own row)
    #pragma unroll
    for (int k = 0; k < WPR; ++k) { U[k] = img[base - LDSTR + k]; D[k] = img[base + LDSTR + k]; }
    u64* egr = eg + ((size_t)b << 12) + (size_t)h * WPR;
    #pragma unroll
    for (int k = 0; k < WPR; ++k) {
        u64 Mc = M[k];
        u64 Uc = U[k], Dc = D[k];
        u64 Up = k     ? U[k-1] : 0ULL;
        u64 Mp = k     ? M[k-1] : 0ULL;
        u64 Dp = k     ? D[k-1] : 0ULL;
        u64 Un = k < 7 ? U[k+1] : 0ULL;
        u64 Mn = k < 7 ? M[k+1] : 0ULL;
        u64 Dn = k < 7 ? D[k+1] : 0ULL;
        u64 P2 = Uc, P6 = Dc;
        u64 P3 = (Uc >> 1) | (Un << 63);
        u64 P4 = (Mc >> 1) | (Mn << 63);
        u64 P5 = (Dc >> 1) | (Dn << 63);
        u64 P9 = (Uc << 1) | (Up >> 63);
        u64 P8 = (Mc << 1) | (Mp >> 63);
        u64 P7 = (Dc << 1) | (Dp >> 63);
        u64 e, seen, two = 0;
        seen = P2;
        e = P3; two |= seen & e; seen |= e;
        e = P4; two |= seen & e; seen |= e;
        e = P5; two |= seen & e; seen |= e;
        e = P6; two |= seen & e; seen |= e;
        e = P7; two |= seen & e; seen |= e;
        e = P8; two |= seen & e; seen |= e;
        e = P9; two |= seen & e; seen |= e;
        egr[k] = Mc & seen & ~two;             // exactly one neighbor
    }
}

// ---------------- packed 9x9 count helpers ----------------
struct Planes { u64 p0, p1, p2, p3; };

__device__ __forceinline__ Planes vcount9(const u64 r[9]) {
    u64 s0,c0, s1,c1, s2,c2, p0,t0, t1,t2, p1,t3, p2,p3;
    FA(r[0],r[1],r[2], s0,c0);
    FA(r[3],r[4],r[5], s1,c1);
    FA(r[6],r[7],r[8], s2,c2);
    FA(s0,s1,s2, p0,t0);
    FA(c0,c1,c2, t1,t2);
    HA(t0,t1,    p1,t3);
    HA(t2,t3,    p2,p3);
    Planes P; P.p0 = p0; P.p1 = p1; P.p2 = p2; P.p3 = p3; return P;
}

__device__ __forceinline__ u64 spread8(u64 bb) {
    u64 s = (bb * 0x0101010101010101ULL) & 0x8040201008040201ULL;
    return ((s + 0x7f7f7f7f7f7f7f7fULL) >> 7) & 0x0101010101010101ULL;
}

__device__ __forceinline__ u64 vbytes(const Planes& P, int g) {
    int s = 8 * g;
    return  spread8((P.p0 >> s) & 0xFFULL)
         + (spread8((P.p1 >> s) & 0xFFULL) << 1)
         + (spread8((P.p2 >> s) & 0xFFULL) << 2)
         + (spread8((P.p3 >> s) & 0xFFULL) << 3);
}

// ---------------- kernel 3: dense weighted sum ----------------
// w_i = 60*n_i + [n_i==0], n_i = 9x9 box count of E;  out = mean(w*L)
__global__ __launch_bounds__(256)
void final_kernel(const float* __restrict__ L, const u64* __restrict__ eg,
                  u64* __restrict__ acc64, u32* __restrict__ ticket,
                  float* __restrict__ out) {
    __shared__ float sm[256];
    int wi = blockIdx.x * blockDim.x + threadIdx.x;   // word index, 32768 total
    int b  = wi >> 12;                                // 4096 words / image
    int h  = (wi >> 3) & (HH - 1);
    int wc = wi & 7;
    const u64* img = eg + ((size_t)b << 12);

    u64 rows[3][9];
    #pragma unroll
    for (int dh = -4; dh <= 4; ++dh) {
        int hh = h + dh;
        bool okh = (unsigned)hh < (unsigned)HH;
        const u64* rp = img + hh * WPR;
        rows[0][dh + 4] = (okh && wc > 0) ? rp[wc - 1] : 0ULL;
        rows[1][dh + 4] = okh             ? rp[wc]     : 0ULL;
        rows[2][dh + 4] = (okh && wc < 7) ? rp[wc + 1] : 0ULL;
    }
    Planes Pm = vcount9(rows[0]);
    Planes Pc = vcount9(rows[1]);
    Planes Pp = vcount9(rows[2]);

    u64 v[10];
    v[0] = vbytes(Pm, 7);
    #pragma unroll
    for (int g = 0; g < 8; ++g) v[g + 1] = vbytes(Pc, g);
    v[9] = vbytes(Pp, 0);

    const float4* Lr = (const float4*)(L + ((size_t)wi << 6));
    float acc = 0.0f;
    #pragma unroll
    for (int g = 0; g < 8; ++g) {
        u64 a = v[g + 1], lo = v[g], hi = v[g + 2];
        u64 n = a;
        #pragma unroll
        for (int d = 1; d <= 4; ++d) {
            n += (a >> (8 * d)) | (hi << (64 - 8 * d));
            n += (a << (8 * d)) | (lo >> (64 - 8 * d));
        }
        float4 f0 = Lr[2 * g], f1 = Lr[2 * g + 1];
        #pragma unroll
        for (int j = 0; j < 8; ++j) {
            int cnt = (int)((n >> (8 * j)) & 0xFFULL);
            float wgt = cnt ? (float)(60 * cnt) : 1.0f;
            float lv = (j < 4) ? ((j == 0) ? f0.x : (j == 1) ? f0.y : (j == 2) ? f0.z : f0.w)
                               : ((j == 4) ? f1.x : (j == 5) ? f1.y : (j == 6) ? f1.z : f1.w);
            acc += wgt * lv;
        }
    }

    sm[threadIdx.x] = acc;
    __syncthreads();
    for (int s = 128; s > 0; s >>= 1) {
        if (threadIdx.x < s) sm[threadIdx.x] += sm[threadIdx.x + s];
        __syncthreads();
    }
    if (threadIdx.x == 0) {
        u64 vfx = (u64)(long long)llrintf(sm[0] * (float)FPSCALE);
        atomicAdd(acc64, vfx);
        __threadfence();
        u32 t = atomicAdd(ticket, 1u);
        if (t == (u32)(gridDim.x - 1)) {           // last block finishes
            __threadfence();
            u64 total = __hip_atomic_load(acc64, __ATOMIC_RELAXED, __HIP_MEMORY_SCOPE_AGENT);
            out[0] = (float)((double)(long long)total / (FPSCALE * (double)NPIX));
        }
    }
}

extern "C" void kernel_launch(void* const* d_in, const int* in_sizes, int n_in,
                              void* d_out, int out_size, void* d_ws, size_t ws_size,
                              hipStream_t stream) {
    const float* pred = (const float*)d_in[0];
    const int* target = (const int*)d_in[1];
    float* out = (float*)d_out;
    char* ws = (char*)d_ws;

    // ws layout (bytes):
    //   [0,        8388608)  L       float[NPIX]
    //   [8388608,  8650752)  xp      u64[NWORDS]  packed mask
    //   [8650752,  8912896)  eg      u64[NWORDS]  packed endpoints
    //   [8912896,  8912904)  acc64   u64
    //   [8912904,  8912908)  ticket  u32
    float* L    = (float*)(ws);
    u64* xp     = (u64*)(ws + 8388608);
    u64* eg     = (u64*)(ws + 8650752);
    u64* acc64  = (u64*)(ws + 8912896);
    u32* ticket = (u32*)(ws + 8912904);

    prep_kernel<<<dim3(NPIX / 256), dim3(256), 0, stream>>>(pred, target, L, xp, acc64, ticket);
    skel_kernel<<<dim3(BATCH), dim3(512), 0, stream>>>(xp, eg);
    final_kernel<<<dim3(NWORDS / 256), dim3(256), 0, stream>>>(L, eg, acc64, ticket, out);
}